// Round 2
// baseline (23.075 us; speedup 1.0000x reference)
//
#include <hip/hip_runtime.h>
#include <hip/hip_bf16.h>

// Segment-mean over sorted indexes, two-phase.
// hidden: [B=8, S=2048, D=768] f32; ori_indexes: [B, S] sorted int (<T=1024)
// out:    [B, T, D] f32 = segment_sum / clip(count,1)
//
// Phase 1: starts[b][t] = lower_bound(idx_row_b, t) for t in [0, T]  (d_ws)
// Phase 2: one block per (b, 4-token tile). Reads 5 uniform boundary ints,
//          then streams the contiguous row range [starts[t0], starts[t0+4])
//          with coalesced float4 loads — no dependent search latency in the
//          streaming kernel. Every output element written exactly once.

#define SGA_B 8
#define SGA_S 2048
#define SGA_D 768
#define SGA_T 1024
#define SGA_TPB 4            // tokens per block in phase 2
#define SGA_NV (SGA_D / 4)   // 192 float4 lanes per row

__global__ __launch_bounds__(256) void sga_offsets_kernel(
    const int* __restrict__ idx, int* __restrict__ starts) {
    const int t = blockIdx.x * 256 + threadIdx.x;   // 0..T (inclusive)
    const int b = blockIdx.y;
    if (t > SGA_T) return;
    const int* ib = idx + b * SGA_S;
    int lo = 0, hi = SGA_S;
    while (lo < hi) {
        int m = (lo + hi) >> 1;
        if (ib[m] < t) lo = m + 1; else hi = m;
    }
    starts[b * (SGA_T + 1) + t] = lo;
}

__global__ __launch_bounds__(SGA_NV) void sga_segmean_kernel(
    const float* __restrict__ hidden,
    const int* __restrict__ starts,
    float* __restrict__ out) {
    const int t0 = blockIdx.x * SGA_TPB;
    const int b = blockIdx.y;
    const int tid = threadIdx.x;

    const int* sb = starts + b * (SGA_T + 1) + t0;
    int bound[SGA_TPB + 1];
#pragma unroll
    for (int i = 0; i <= SGA_TPB; ++i) bound[i] = sb[i];

    const float4* __restrict__ hrow =
        reinterpret_cast<const float4*>(hidden) + (size_t)b * SGA_S * SGA_NV;
    float4* __restrict__ orow =
        reinterpret_cast<float4*>(out) + ((size_t)b * SGA_T + t0) * SGA_NV;

#pragma unroll
    for (int k = 0; k < SGA_TPB; ++k) {
        const int s0 = bound[k], s1 = bound[k + 1];
        float4 acc = make_float4(0.f, 0.f, 0.f, 0.f);
        for (int s = s0; s < s1; ++s) {
            float4 v = hrow[(size_t)s * SGA_NV + tid];
            acc.x += v.x; acc.y += v.y; acc.z += v.z; acc.w += v.w;
        }
        const float inv = (s1 > s0) ? (1.0f / (float)(s1 - s0)) : 0.0f;
        acc.x *= inv; acc.y *= inv; acc.z *= inv; acc.w *= inv;
        orow[(size_t)k * SGA_NV + tid] = acc;
    }
}

// Fallback (R0 path): single kernel with in-block binary search, used only
// if ws_size can't hold the offsets table.
__global__ __launch_bounds__(SGA_NV) void sga_segmean_search_kernel(
    const float* __restrict__ hidden,
    const int* __restrict__ idx,
    float* __restrict__ out) {
    const int t = blockIdx.x;
    const int b = blockIdx.y;
    const int tid = threadIdx.x;
    const int* ib = idx + b * SGA_S;
    int lo = 0, hi = SGA_S;
    while (lo < hi) { int m = (lo + hi) >> 1; if (ib[m] < t) lo = m + 1; else hi = m; }
    const int start = lo;
    hi = SGA_S;
    while (lo < hi) { int m = (lo + hi) >> 1; if (ib[m] < t + 1) lo = m + 1; else hi = m; }
    const int end = lo;
    const float inv = (end > start) ? (1.0f / (float)(end - start)) : 0.0f;
    const float4* __restrict__ hrow =
        reinterpret_cast<const float4*>(hidden) + (size_t)b * SGA_S * SGA_NV;
    float4 acc = make_float4(0.f, 0.f, 0.f, 0.f);
    for (int s = start; s < end; ++s) {
        float4 v = hrow[(size_t)s * SGA_NV + tid];
        acc.x += v.x; acc.y += v.y; acc.z += v.z; acc.w += v.w;
    }
    acc.x *= inv; acc.y *= inv; acc.z *= inv; acc.w *= inv;
    reinterpret_cast<float4*>(out)[((size_t)b * SGA_T + t) * SGA_NV + tid] = acc;
}

extern "C" void kernel_launch(void* const* d_in, const int* in_sizes, int n_in,
                              void* d_out, int out_size, void* d_ws, size_t ws_size,
                              hipStream_t stream) {
    const float* hidden = (const float*)d_in[0];
    const int* idx = (const int*)d_in[1];
    float* out = (float*)d_out;

    const size_t table_bytes = (size_t)SGA_B * (SGA_T + 1) * sizeof(int);
    if (ws_size >= table_bytes && d_ws != nullptr) {
        int* starts = (int*)d_ws;
        {
            dim3 grid((SGA_T + 1 + 255) / 256, SGA_B, 1);
            sga_offsets_kernel<<<grid, dim3(256, 1, 1), 0, stream>>>(idx, starts);
        }
        {
            dim3 grid(SGA_T / SGA_TPB, SGA_B, 1);
            sga_segmean_kernel<<<grid, dim3(SGA_NV, 1, 1), 0, stream>>>(hidden, starts, out);
        }
    } else {
        dim3 grid(SGA_T, SGA_B, 1);
        sga_segmean_search_kernel<<<grid, dim3(SGA_NV, 1, 1), 0, stream>>>(hidden, idx, out);
    }
}

// Round 3
// 19.800 us; speedup vs baseline: 1.1654x; 1.1654x over previous
//
#include <hip/hip_runtime.h>
#include <hip/hip_bf16.h>

// Segment-mean over sorted indexes — single dispatch, wave-per-token.
// hidden: [B=8, S=2048, D=768] f32; ori_indexes: [B, S] sorted int (<T=1024)
// out:    [B, T, D] f32 = segment_sum / clip(count,1)
//
// Block = 256 threads = 4 waves; wave w owns token t = blockIdx.x*4 + w.
// Sorted indexes -> token t's rows are [lower_bound(t), lower_bound(t+1)),
// found by two uniform binary searches over the L1-resident 8KB index row.
// Lane l accumulates float4 columns {l, l+64, l+128}; row loop unrolled x2
// -> 6 independent 1KB loads in flight per wave. Nontemporal hints (pure
// streaming, no reuse). Every output element written exactly once; zero-count
// tokens write 0 -> deterministic, no pre-zeroing needed.

#define SGA_B 8
#define SGA_S 2048
#define SGA_D 768
#define SGA_T 1024
#define SGA_NV (SGA_D / 4)   // 192 float4 per row

typedef float f32x4 __attribute__((ext_vector_type(4)));

__global__ __launch_bounds__(256) void sga_segmean_kernel(
    const float* __restrict__ hidden,
    const int* __restrict__ idx,
    float* __restrict__ out) {
    const int b = blockIdx.y;
    const int wid = threadIdx.x >> 6;
    const int lane = threadIdx.x & 63;
    const int t = blockIdx.x * 4 + wid;   // 0..T-1

    const int* __restrict__ ib = idx + b * SGA_S;

    // lower_bound(t), then lower_bound(t+1) continuing from it (wave-uniform)
    int lo = 0, hi = SGA_S;
    while (lo < hi) { int m = (lo + hi) >> 1; if (ib[m] < t) lo = m + 1; else hi = m; }
    const int s0 = lo;
    hi = SGA_S;
    while (lo < hi) { int m = (lo + hi) >> 1; if (ib[m] < t + 1) lo = m + 1; else hi = m; }
    const int s1 = lo;

    const f32x4* __restrict__ hbase =
        reinterpret_cast<const f32x4*>(hidden) + (size_t)b * SGA_S * SGA_NV + lane;

    f32x4 a0 = (f32x4)0.f, a1 = (f32x4)0.f, a2 = (f32x4)0.f;

    int s = s0;
    for (; s + 1 < s1; s += 2) {
        const f32x4* r0 = hbase + (size_t)s * SGA_NV;
        const f32x4* r1 = r0 + SGA_NV;
        f32x4 v00 = __builtin_nontemporal_load(r0);
        f32x4 v01 = __builtin_nontemporal_load(r0 + 64);
        f32x4 v02 = __builtin_nontemporal_load(r0 + 128);
        f32x4 v10 = __builtin_nontemporal_load(r1);
        f32x4 v11 = __builtin_nontemporal_load(r1 + 64);
        f32x4 v12 = __builtin_nontemporal_load(r1 + 128);
        a0 += v00; a1 += v01; a2 += v02;
        a0 += v10; a1 += v11; a2 += v12;
    }
    if (s < s1) {
        const f32x4* r0 = hbase + (size_t)s * SGA_NV;
        a0 += __builtin_nontemporal_load(r0);
        a1 += __builtin_nontemporal_load(r0 + 64);
        a2 += __builtin_nontemporal_load(r0 + 128);
    }

    const int cnt = s1 - s0;
    const float inv = (cnt > 0) ? (1.0f / (float)cnt) : 0.0f;
    a0 *= inv; a1 *= inv; a2 *= inv;

    f32x4* __restrict__ obase =
        reinterpret_cast<f32x4*>(out) + ((size_t)b * SGA_T + t) * SGA_NV + lane;
    __builtin_nontemporal_store(a0, obase);
    __builtin_nontemporal_store(a1, obase + 64);
    __builtin_nontemporal_store(a2, obase + 128);
}

extern "C" void kernel_launch(void* const* d_in, const int* in_sizes, int n_in,
                              void* d_out, int out_size, void* d_ws, size_t ws_size,
                              hipStream_t stream) {
    const float* hidden = (const float*)d_in[0];
    const int* idx = (const int*)d_in[1];
    float* out = (float*)d_out;

    dim3 grid(SGA_T / 4, SGA_B, 1);   // 256 x 8 blocks, 4 waves each
    sga_segmean_kernel<<<grid, dim3(256, 1, 1), 0, stream>>>(hidden, idx, out);
}